// Round 1
// baseline (16133.534 us; speedup 1.0000x reference)
//
#include <hip/hip_runtime.h>

// Problem constants (fixed by the reference)
constexpr int Bc = 64;      // batch
constexpr int Tc = 2048;    // time steps
constexpr int Ic = 3;       // input dim
constexpr int Hc = 512;     // hidden
constexpr float AL = 0.2f;  // ALPHA
constexpr float NS = 0.05f; // NOISE_STD

// ---------------------------------------------------------------------------
// Kernel 1: build W^T  (WT[k][h] = w_rec[h][k] = sum_r m[h,r] n[k,r]/H + rec_noise[h,k])
// Transposed layout so the scan kernel's wave loads are contiguous over h.
// ---------------------------------------------------------------------------
__global__ void prep_wt(const float* __restrict__ m, const float* __restrict__ n,
                        const float* __restrict__ rn, float* __restrict__ WT, int R) {
    int id = blockIdx.x * 256 + threadIdx.x;
    if (id >= Hc * Hc) return;
    int k = id >> 9;          // WT row
    int h = id & (Hc - 1);    // WT col (contiguous per wave -> coalesced store)
    float acc = rn[h * Hc + k];
    for (int r = 0; r < R; ++r)
        acc = fmaf(m[h * R + r], n[k * R + r] * (1.0f / Hc), acc);
    WT[id] = acc;
}

// ---------------------------------------------------------------------------
// Kernel 2: the sequential scan. One block per batch element.
// 512 threads = 8 waves. Thread t owns h[t]. Matvec: 4 k-groups x 128 lanes,
// each thread produces 4 h-partials from a 128-wide k slice, reduced via LDS.
// ---------------------------------------------------------------------------
__launch_bounds__(512)
__global__ void rnn_scan(const float* __restrict__ input, const float* __restrict__ noise,
                         const float* __restrict__ w_i, const float* __restrict__ s_i,
                         const float* __restrict__ WT, const float* __restrict__ w_o,
                         const float* __restrict__ s_o, const float* __restrict__ h0,
                         float* __restrict__ out, float* __restrict__ part) {
    __shared__ float r_lds[Hc];      // tanh(h) broadcast buffer
    __shared__ float pl[4][Hc];      // k-group partials
    __shared__ float wi_lds[Ic][Hc]; // w_i * s_i
    __shared__ float red[8];         // per-wave output partials (fallback path)

    const int tid = threadIdx.x;
    const int b   = blockIdx.x;
    const int g   = tid >> 7;   // k-group 0..3 (k in [128g, 128g+128))
    const int j   = tid & 127;  // handles h = 4j..4j+3 in the matvec phase

    for (int i = 0; i < Ic; ++i)
        wi_lds[i][tid] = w_i[i * Hc + tid] * s_i[i];

    float h = h0[tid];
    float r_cur = tanhf(h);
    const float wo_h = w_o[tid] * s_o[0] * (1.0f / Hc);

    const float* noise_b = noise + (size_t)b * Tc * Hc;
    const float* inp_b   = input + (size_t)b * Tc * Ic;

    // software prefetch state (one step ahead)
    float nz = noise_b[tid];
    float i0 = inp_b[0], i1 = inp_b[1], i2 = inp_b[2];

    const float* Wg = WT + (g * 128) * Hc + 4 * j; // my k-slice, my 4 columns
    const float* rg = r_lds + g * 128;

    __syncthreads();

    for (int t = 0; t < Tc; ++t) {
        // issue next-step input loads now; consumed at the end of the loop body
        const int tn = (t + 1 < Tc) ? t + 1 : t;
        const float nz_n = noise_b[(size_t)tn * Hc + tid];
        const float i0n = inp_b[tn * Ic + 0];
        const float i1n = inp_b[tn * Ic + 1];
        const float i2n = inp_b[tn * Ic + 2];

        r_lds[tid] = r_cur;
        __syncthreads();

        // partial matvec: acc[c] = sum_{k in slice} r[k] * WT[k][4j+c]
        float a0 = 0.f, a1 = 0.f, a2 = 0.f, a3 = 0.f;
        #pragma unroll 4
        for (int kk = 0; kk < 128; kk += 4) {
            const float4 rv = *(const float4*)(rg + kk);               // LDS broadcast
            const float4 w0 = *(const float4*)(Wg + (kk + 0) * Hc);    // coalesced 1KB/wave
            const float4 w1 = *(const float4*)(Wg + (kk + 1) * Hc);
            const float4 w2 = *(const float4*)(Wg + (kk + 2) * Hc);
            const float4 w3 = *(const float4*)(Wg + (kk + 3) * Hc);
            a0 = fmaf(rv.x, w0.x, a0); a0 = fmaf(rv.y, w1.x, a0);
            a0 = fmaf(rv.z, w2.x, a0); a0 = fmaf(rv.w, w3.x, a0);
            a1 = fmaf(rv.x, w0.y, a1); a1 = fmaf(rv.y, w1.y, a1);
            a1 = fmaf(rv.z, w2.y, a1); a1 = fmaf(rv.w, w3.y, a1);
            a2 = fmaf(rv.x, w0.z, a2); a2 = fmaf(rv.y, w1.z, a2);
            a2 = fmaf(rv.z, w2.z, a2); a2 = fmaf(rv.w, w3.z, a2);
            a3 = fmaf(rv.x, w0.w, a3); a3 = fmaf(rv.y, w1.w, a3);
            a3 = fmaf(rv.z, w2.w, a3); a3 = fmaf(rv.w, w3.w, a3);
        }
        *(float4*)&pl[g][4 * j] = make_float4(a0, a1, a2, a3);
        __syncthreads();

        // state update for h = tid
        const float y  = pl[0][tid] + pl[1][tid] + pl[2][tid] + pl[3][tid];
        const float di = i0 * wi_lds[0][tid] + i1 * wi_lds[1][tid] + i2 * wi_lds[2][tid];
        h = h + (NS * nz + AL * di) + AL * (y - h);
        r_cur = tanhf(h);

        // output partial: sum_h r_new[h] * wo[h] / H
        float p = r_cur * wo_h;
        #pragma unroll
        for (int off = 32; off; off >>= 1) p += __shfl_xor(p, off, 64);
        if (part) {
            if ((tid & 63) == 0)
                part[((size_t)b * Tc + t) * 8 + (tid >> 6)] = p; // epilogue reduces
        } else {
            if ((tid & 63) == 0) red[tid >> 6] = p;
            __syncthreads();
            if (tid == 0)
                out[(size_t)b * Tc + t] = red[0] + red[1] + red[2] + red[3] +
                                          red[4] + red[5] + red[6] + red[7];
        }

        nz = nz_n; i0 = i0n; i1 = i1n; i2 = i2n;
    }
}

// ---------------------------------------------------------------------------
// Kernel 3: reduce the 8 per-wave partials -> out[b*T+t]
// ---------------------------------------------------------------------------
__global__ void out_reduce(const float* __restrict__ part, float* __restrict__ out, int n) {
    int id = blockIdx.x * 256 + threadIdx.x;
    if (id >= n) return;
    const float4* p = (const float4*)(part + (size_t)id * 8);
    float4 x = p[0], y4 = p[1];
    out[id] = ((x.x + x.y) + (x.z + x.w)) + ((y4.x + y4.y) + (y4.z + y4.w));
}

extern "C" void kernel_launch(void* const* d_in, const int* in_sizes, int n_in,
                              void* d_out, int out_size, void* d_ws, size_t ws_size,
                              hipStream_t stream) {
    (void)n_in; (void)out_size;
    const float* input     = (const float*)d_in[0];
    const float* noise     = (const float*)d_in[1];
    const float* w_i       = (const float*)d_in[2];
    const float* s_i       = (const float*)d_in[3];
    const float* m_rec     = (const float*)d_in[4];
    const float* n_rec     = (const float*)d_in[5];
    const float* rec_noise = (const float*)d_in[6];
    const float* w_o       = (const float*)d_in[7];
    const float* s_o       = (const float*)d_in[8];
    const float* h0        = (const float*)d_in[9];
    float* out = (float*)d_out;

    const int R = in_sizes[4] / Hc; // rank of the low-rank term (1 here)

    float* WT = (float*)d_ws;
    const size_t wt_bytes   = (size_t)Hc * Hc * sizeof(float);
    const size_t part_bytes = (size_t)Bc * Tc * 8 * sizeof(float);
    float* part = (ws_size >= wt_bytes + part_bytes)
                      ? (float*)((char*)d_ws + wt_bytes) : nullptr;

    prep_wt<<<(Hc * Hc + 255) / 256, 256, 0, stream>>>(m_rec, n_rec, rec_noise, WT, R);
    rnn_scan<<<Bc, 512, 0, stream>>>(input, noise, w_i, s_i, WT, w_o, s_o, h0, out, part);
    if (part)
        out_reduce<<<(Bc * Tc + 255) / 256, 256, 0, stream>>>(part, out, Bc * Tc);
}

// Round 2
// 3875.207 us; speedup vs baseline: 4.1633x; 4.1633x over previous
//
#include <hip/hip_runtime.h>

// Problem constants (fixed by the reference)
constexpr int Bc = 64;      // batch
constexpr int Tc = 2048;    // time steps
constexpr int Ic = 3;       // input dim
constexpr int Hc = 512;     // hidden
constexpr float AL = 0.2f;  // ALPHA
constexpr float NS = 0.05f; // NOISE_STD
constexpr int NSL = 4;      // slices (blocks) per batch
constexpr int HS  = Hc / NSL; // 128 h per slice

// d_ws layout:
//   [0, 1MB)          WT fp32 [512][512]  (WT[k][h] = w_rec[h][k])
//   [1MB, 1MB+512KB)  rbuf u64 [64 batches][2 parity][512 h]  = {tag<<32 | f32bits}
// ---------------------------------------------------------------------------
__global__ void prep_wt(const float* __restrict__ m, const float* __restrict__ n,
                        const float* __restrict__ rn, float* __restrict__ WT, int R) {
    int id = blockIdx.x * 256 + threadIdx.x;
    if (id >= Hc * Hc) return;
    int k = id >> 9;
    int h = id & (Hc - 1);
    float acc = rn[h * Hc + k];
    for (int r = 0; r < R; ++r)
        acc = fmaf(m[h * R + r], n[k * R + r] * (1.0f / Hc), acc);
    WT[id] = acc;
}

// ---------------------------------------------------------------------------
// 4 blocks per batch, h-split. W slice register-resident (128 fp32/thread).
// Cross-block r exchange: per-word {tag,val} atomics, tag = t+1, parity dbuf.
// ---------------------------------------------------------------------------
__launch_bounds__(512, 1)
__global__ void rnn4(const float* __restrict__ input, const float* __restrict__ noise,
                     const float* __restrict__ w_i, const float* __restrict__ s_i,
                     const float* __restrict__ WT, const float* __restrict__ w_o,
                     const float* __restrict__ s_o, const float* __restrict__ h0,
                     float* __restrict__ out, unsigned long long* __restrict__ rbuf) {
    __shared__ float r_lds[Hc];      // full r_t
    __shared__ float pl[NSL][HS];    // k-group matvec partials
    __shared__ float red[8];         // output reduce

    const int tid = threadIdx.x;
    const int s   = blockIdx.x >> 6;   // slice 0..3  (owns h in [128s, 128s+128))
    const int b   = blockIdx.x & 63;   // batch
    const int g   = tid >> 7;          // k-group 0..3 (k in [128g, 128g+128))
    const int j   = tid & 127;         // column within slice: h = 128s + j
    const int hbase = s * HS;

    // --- register-resident W slice: w[kk] = WT[128g+kk][hbase+j] ---
    float w[128];
    const float* Wp = WT + (size_t)(g * 128) * Hc + hbase + j;
    #pragma unroll
    for (int kk = 0; kk < 128; ++kk) w[kk] = Wp[(size_t)kk * Hc];

    const float wo_t = w_o[tid] * s_o[0] * (1.0f / Hc);

    // per-owned-h state (threads tid<128 own h = hbase+tid)
    float h = 0.f, wi0 = 0.f, wi1 = 0.f, wi2 = 0.f;
    if (tid < HS) {
        h   = h0[hbase + tid];
        wi0 = w_i[0 * Hc + hbase + tid] * s_i[0];
        wi1 = w_i[1 * Hc + hbase + tid] * s_i[1];
        wi2 = w_i[2 * Hc + hbase + tid] * s_i[2];
    }
    r_lds[tid] = tanhf(h0[tid]);   // r_0, locally computable by everyone

    const float* noise_b = noise + (size_t)b * Tc * Hc;
    const float* inp_b   = input + (size_t)b * Tc * Ic;
    unsigned long long* rb_b = rbuf + (size_t)b * 2 * Hc;

    float nz = (tid < HS) ? noise_b[hbase + tid] : 0.f;
    float i0 = inp_b[0], i1 = inp_b[1], i2 = inp_b[2];
    __syncthreads();

    for (int t = 0; t < Tc; ++t) {
        // prefetch next step's drive inputs
        const int tn = (t + 1 < Tc) ? t + 1 : t;
        const float nz_n = (tid < HS) ? noise_b[(size_t)tn * Hc + hbase + tid] : 0.f;
        const float i0n = inp_b[tn * Ic + 0];
        const float i1n = inp_b[tn * Ic + 1];
        const float i2n = inp_b[tn * Ic + 2];

        // --- matvec partial: y_part = sum_{k in group} r[k] * W[h][k] ---
        const float* rg = r_lds + g * 128;
        float a0 = 0.f, a1 = 0.f, a2 = 0.f, a3 = 0.f;
        #pragma unroll
        for (int kk = 0; kk < 128; kk += 4) {
            const float4 rv = *(const float4*)(rg + kk);  // wave-uniform addr -> LDS broadcast
            a0 = fmaf(w[kk + 0], rv.x, a0);
            a1 = fmaf(w[kk + 1], rv.y, a1);
            a2 = fmaf(w[kk + 2], rv.z, a2);
            a3 = fmaf(w[kk + 3], rv.w, a3);
        }
        pl[g][j] = (a0 + a1) + (a2 + a3);
        __syncthreads();                                   // SYNC1

        const unsigned want = (unsigned)(t + 1);
        unsigned long long* slot = rb_b + ((size_t)((t + 1) & 1)) * Hc;

        if (tid < HS) {
            const float y  = pl[0][tid] + pl[1][tid] + pl[2][tid] + pl[3][tid];
            const float di = i0 * wi0 + i1 * wi1 + i2 * wi2;
            h = h + (NS * nz + AL * di) + AL * (y - h);
            const float rv = tanhf(h);
            r_lds[hbase + tid] = rv;  // own slice goes straight to LDS
            const unsigned long long word =
                ((unsigned long long)want << 32) | (unsigned long long)__float_as_uint(rv);
            __hip_atomic_store(&slot[hbase + tid], word,
                               __ATOMIC_RELAXED, __HIP_MEMORY_SCOPE_AGENT);
        }

        // --- poll the 3 foreign slices (one word per thread) ---
        if ((tid >> 7) != s) {
            const unsigned long long* myp = &slot[tid];
            unsigned long long v;
            for (;;) {
                v = __hip_atomic_load(myp, __ATOMIC_RELAXED, __HIP_MEMORY_SCOPE_AGENT);
                if ((unsigned)(v >> 32) == want) break;
                __builtin_amdgcn_s_sleep(1);
            }
            r_lds[tid] = __uint_as_float((unsigned)v);
        }
        __syncthreads();                                   // SYNC2: full r_{t+1} in LDS

        // --- output for this step, rotated across the 4 slice-blocks ---
        if ((t & 3) == s) {
            float p = r_lds[tid] * wo_t;
            #pragma unroll
            for (int off = 32; off; off >>= 1) p += __shfl_xor(p, off, 64);
            if ((tid & 63) == 0) red[tid >> 6] = p;
            __syncthreads();                               // SYNC3
            if (tid == 0)
                out[(size_t)b * Tc + t] = red[0] + red[1] + red[2] + red[3] +
                                          red[4] + red[5] + red[6] + red[7];
        }

        nz = nz_n; i0 = i0n; i1 = i1n; i2 = i2n;
    }
}

// ---------------------------------------------------------------------------
// Fallback (round-1 kernel, direct-out path) if d_ws is too small — safety net.
// ---------------------------------------------------------------------------
__launch_bounds__(512)
__global__ void rnn_scan_fb(const float* __restrict__ input, const float* __restrict__ noise,
                            const float* __restrict__ w_i, const float* __restrict__ s_i,
                            const float* __restrict__ WT, const float* __restrict__ w_o,
                            const float* __restrict__ s_o, const float* __restrict__ h0,
                            float* __restrict__ out) {
    __shared__ float r_lds[Hc];
    __shared__ float pl[4][Hc];
    __shared__ float wi_lds[Ic][Hc];
    __shared__ float red[8];

    const int tid = threadIdx.x;
    const int b   = blockIdx.x;
    const int g   = tid >> 7;
    const int j   = tid & 127;

    for (int i = 0; i < Ic; ++i) wi_lds[i][tid] = w_i[i * Hc + tid] * s_i[i];

    float h = h0[tid];
    float r_cur = tanhf(h);
    const float wo_h = w_o[tid] * s_o[0] * (1.0f / Hc);
    const float* noise_b = noise + (size_t)b * Tc * Hc;
    const float* inp_b   = input + (size_t)b * Tc * Ic;
    float nz = noise_b[tid];
    float i0 = inp_b[0], i1 = inp_b[1], i2 = inp_b[2];
    const float* Wg = WT + (g * 128) * Hc + 4 * j;
    const float* rg = r_lds + g * 128;
    __syncthreads();

    for (int t = 0; t < Tc; ++t) {
        const int tn = (t + 1 < Tc) ? t + 1 : t;
        const float nz_n = noise_b[(size_t)tn * Hc + tid];
        const float i0n = inp_b[tn * Ic + 0];
        const float i1n = inp_b[tn * Ic + 1];
        const float i2n = inp_b[tn * Ic + 2];

        r_lds[tid] = r_cur;
        __syncthreads();
        float a0 = 0.f, a1 = 0.f, a2 = 0.f, a3 = 0.f;
        #pragma unroll 4
        for (int kk = 0; kk < 128; kk += 4) {
            const float4 rv = *(const float4*)(rg + kk);
            const float4 w0 = *(const float4*)(Wg + (kk + 0) * Hc);
            const float4 w1 = *(const float4*)(Wg + (kk + 1) * Hc);
            const float4 w2 = *(const float4*)(Wg + (kk + 2) * Hc);
            const float4 w3 = *(const float4*)(Wg + (kk + 3) * Hc);
            a0 = fmaf(rv.x, w0.x, a0); a0 = fmaf(rv.y, w1.x, a0);
            a0 = fmaf(rv.z, w2.x, a0); a0 = fmaf(rv.w, w3.x, a0);
            a1 = fmaf(rv.x, w0.y, a1); a1 = fmaf(rv.y, w1.y, a1);
            a1 = fmaf(rv.z, w2.y, a1); a1 = fmaf(rv.w, w3.y, a1);
            a2 = fmaf(rv.x, w0.z, a2); a2 = fmaf(rv.y, w1.z, a2);
            a2 = fmaf(rv.z, w2.z, a2); a2 = fmaf(rv.w, w3.z, a2);
            a3 = fmaf(rv.x, w0.w, a3); a3 = fmaf(rv.y, w1.w, a3);
            a3 = fmaf(rv.z, w2.w, a3); a3 = fmaf(rv.w, w3.w, a3);
        }
        *(float4*)&pl[g][4 * j] = make_float4(a0, a1, a2, a3);
        __syncthreads();

        const float y  = pl[0][tid] + pl[1][tid] + pl[2][tid] + pl[3][tid];
        const float di = i0 * wi_lds[0][tid] + i1 * wi_lds[1][tid] + i2 * wi_lds[2][tid];
        h = h + (NS * nz + AL * di) + AL * (y - h);
        r_cur = tanhf(h);

        float p = r_cur * wo_h;
        #pragma unroll
        for (int off = 32; off; off >>= 1) p += __shfl_xor(p, off, 64);
        if ((tid & 63) == 0) red[tid >> 6] = p;
        __syncthreads();
        if (tid == 0)
            out[(size_t)b * Tc + t] = red[0] + red[1] + red[2] + red[3] +
                                      red[4] + red[5] + red[6] + red[7];
        nz = nz_n; i0 = i0n; i1 = i1n; i2 = i2n;
    }
}

extern "C" void kernel_launch(void* const* d_in, const int* in_sizes, int n_in,
                              void* d_out, int out_size, void* d_ws, size_t ws_size,
                              hipStream_t stream) {
    (void)n_in; (void)out_size;
    const float* input     = (const float*)d_in[0];
    const float* noise     = (const float*)d_in[1];
    const float* w_i       = (const float*)d_in[2];
    const float* s_i       = (const float*)d_in[3];
    const float* m_rec     = (const float*)d_in[4];
    const float* n_rec     = (const float*)d_in[5];
    const float* rec_noise = (const float*)d_in[6];
    const float* w_o       = (const float*)d_in[7];
    const float* s_o       = (const float*)d_in[8];
    const float* h0        = (const float*)d_in[9];
    float* out = (float*)d_out;

    const int R = in_sizes[4] / Hc;

    float* WT = (float*)d_ws;
    const size_t wt_bytes = (size_t)Hc * Hc * sizeof(float);
    const size_t rb_bytes = (size_t)Bc * 2 * Hc * sizeof(unsigned long long);

    prep_wt<<<(Hc * Hc + 255) / 256, 256, 0, stream>>>(m_rec, n_rec, rec_noise, WT, R);

    if (ws_size >= wt_bytes + rb_bytes) {
        unsigned long long* rbuf = (unsigned long long*)((char*)d_ws + wt_bytes);
        hipMemsetAsync(rbuf, 0, rb_bytes, stream);  // reset tags every call (replay-safe)
        rnn4<<<NSL * Bc, 512, 0, stream>>>(input, noise, w_i, s_i, WT, w_o, s_o, h0,
                                           out, rbuf);
    } else {
        rnn_scan_fb<<<Bc, 512, 0, stream>>>(input, noise, w_i, s_i, WT, w_o, s_o, h0, out);
    }
}

// Round 3
// 3801.671 us; speedup vs baseline: 4.2438x; 1.0193x over previous
//
#include <hip/hip_runtime.h>

// Problem constants (fixed by the reference)
constexpr int Bc = 64;      // batch
constexpr int Tc = 2048;    // time steps
constexpr int Ic = 3;       // input dim
constexpr int Hc = 512;     // hidden
constexpr float AL = 0.2f;  // ALPHA
constexpr float NS = 0.05f; // NOISE_STD
constexpr int NSL = 4;      // slices (blocks) per batch
constexpr int HS  = Hc / NSL; // 128 h per slice
constexpr int PAD = 132;    // padded slice stride in LDS (bank shift 4/slice)

// d_ws layout:
//   [0, 1MB)          WT fp32 [512][512]  (WT[k][h] = w_rec[h][k])
//   [1MB, 1MB+512KB)  rbuf u64 [64 batches][2 parity][512 h] = {tag<<32 | f32bits}
// ---------------------------------------------------------------------------
__global__ void prep_wt(const float* __restrict__ m, const float* __restrict__ n,
                        const float* __restrict__ rn, float* __restrict__ WT, int R) {
    int id = blockIdx.x * 256 + threadIdx.x;
    if (id >= Hc * Hc) return;
    int k = id >> 9;
    int h = id & (Hc - 1);
    float acc = rn[h * Hc + k];
    for (int r = 0; r < R; ++r)
        acc = fmaf(m[h * R + r], n[k * R + r] * (1.0f / Hc), acc);
    WT[id] = acc;
}

// L2-coherent poll load: bypass L1 (sc0), hit the XCD-shared L2.
__device__ __forceinline__ unsigned long long ld_sc0(const unsigned long long* p) {
    unsigned long long v;
    asm volatile("global_load_dwordx2 %0, %1, off sc0\n\t"
                 "s_waitcnt vmcnt(0)"
                 : "=v"(v) : "v"(p) : "memory");
    return v;
}

// ---------------------------------------------------------------------------
// 4 blocks per batch, h-split. W slice PINNED in VGPRs (128 fp32/thread).
// Thread layout: h_local = tid>>2 (0..127), kg = tid&3 (k-group of 128).
// Quad shfl_xor reduces the 4 k-partials -> one barrier per step.
// Cross-block r exchange: {tag,val} u64, agent-scope publish, hybrid
// sc0(L2)/agent(MALL) polling. Parity-double-buffered r in LDS.
// ---------------------------------------------------------------------------
__launch_bounds__(512, 1)
__global__ void rnn4r(const float* __restrict__ input, const float* __restrict__ noise,
                      const float* __restrict__ w_i, const float* __restrict__ s_i,
                      const float* __restrict__ WT, const float* __restrict__ w_o,
                      const float* __restrict__ s_o, const float* __restrict__ h0,
                      float* __restrict__ out, unsigned long long* __restrict__ rbuf) {
    __shared__ float rp[2][NSL * PAD];   // parity-double-buffered r (padded slices)
    __shared__ float red[8];             // output reduce scratch

    const int tid   = threadIdx.x;
    const int s     = blockIdx.x >> 6;   // slice 0..3 (owns h in [128s,128s+128))
    const int b     = blockIdx.x & 63;   // batch
    const int hl    = tid >> 2;          // local h 0..127
    const int kg    = tid & 3;           // k-group (k in [128kg,128kg+128))
    const int hbase = s * HS;
    const int hmy   = hbase + hl;

    // --- load + PIN the W slice in registers: w[kk] = W[hmy][kg*128+kk] ---
    float w[128];
    const float* Wp = WT + (size_t)(kg * 128) * Hc + hmy;
    #pragma unroll
    for (int kk = 0; kk < 128; ++kk) w[kk] = Wp[(size_t)kk * Hc];
    #pragma unroll
    for (int kk = 0; kk < 128; ++kk) asm volatile("" : "+v"(w[kk])); // no remat

    const float wo_t = w_o[tid] * s_o[0] * (1.0f / Hc);
    float h = h0[hmy];
    const float wi0 = w_i[0 * Hc + hmy] * s_i[0];
    const float wi1 = w_i[1 * Hc + hmy] * s_i[1];
    const float wi2 = w_i[2 * Hc + hmy] * s_i[2];

    // r_0 into parity-0 buffer (all 512 h, locally computable)
    rp[0][(tid >> 7) * PAD + (tid & 127)] = tanhf(h0[tid]);

    const float* noise_b = noise + (size_t)b * Tc * Hc;
    const float* inp_b   = input + (size_t)b * Tc * Ic;
    unsigned long long* rb_b = rbuf + (size_t)b * 2 * Hc;

    float nz = noise_b[hmy];
    float i0 = inp_b[0], i1 = inp_b[1], i2 = inp_b[2];

    // poller assignment: threads 0..383 <-> the 384 foreign h-words
    const int ft   = tid + ((tid >= hbase) ? 128 : 0);
    const int fpos = (ft >> 7) * PAD + (ft & 127);
    __syncthreads();

    for (int t = 0; t < Tc; ++t) {
        // prefetch next step's drive inputs
        const int tn = (t + 1 < Tc) ? t + 1 : t;
        const float nz_n = noise_b[(size_t)tn * Hc + hmy];
        const float i0n = inp_b[tn * Ic + 0];
        const float i1n = inp_b[tn * Ic + 1];
        const float i2n = inp_b[tn * Ic + 2];

        // --- matvec partial over my k-group (W in regs, r broadcast from LDS) ---
        const float* rg = &rp[t & 1][kg * PAD];
        float a0 = 0.f, a1 = 0.f, a2 = 0.f, a3 = 0.f;
        #pragma unroll
        for (int kk = 0; kk < 128; kk += 4) {
            const float4 rv = *(const float4*)(rg + kk);  // conflict-free (pad 132)
            a0 = fmaf(w[kk + 0], rv.x, a0);
            a1 = fmaf(w[kk + 1], rv.y, a1);
            a2 = fmaf(w[kk + 2], rv.z, a2);
            a3 = fmaf(w[kk + 3], rv.w, a3);
        }
        float y = (a0 + a1) + (a2 + a3);
        y += __shfl_xor(y, 1, 64);   // quad butterfly: all 4 lanes get the
        y += __shfl_xor(y, 2, 64);   // full k-sum for their h

        // --- state update (redundant across the quad, bitwise identical) ---
        const float di = i0 * wi0 + i1 * wi1 + i2 * wi2;
        h = h + (NS * nz + AL * di) + AL * (y - h);
        const float rv_ = tanhf(h);

        const unsigned want = (unsigned)(t + 1);
        unsigned long long* slot = rb_b + ((size_t)((t + 1) & 1)) * Hc;
        float* wp_ = &rp[(t + 1) & 1][0];

        if (kg == 0) {  // one lane per h publishes + writes own LDS slice
            __hip_atomic_store(&slot[hmy],
                               ((unsigned long long)want << 32) |
                               (unsigned long long)__float_as_uint(rv_),
                               __ATOMIC_RELAXED, __HIP_MEMORY_SCOPE_AGENT);
            wp_[s * PAD + hl] = rv_;
        }

        // --- poll the 384 foreign words: 3x sc0 (L2) : 1x agent (MALL) ---
        if (tid < 384) {
            const unsigned long long* p = &slot[ft];
            unsigned long long v;
            int it = 0;
            for (;;) {
                if ((it & 3) != 3)
                    v = ld_sc0(p);
                else
                    v = __hip_atomic_load(p, __ATOMIC_RELAXED, __HIP_MEMORY_SCOPE_AGENT);
                if ((unsigned)(v >> 32) == want) break;
                ++it;
            }
            wp_[fpos] = __uint_as_float((unsigned)v);
        }
        __syncthreads();   // r_{t+1} complete in rp[(t+1)&1]

        // --- output for step t, rotated across the 4 slice-blocks ---
        if ((t & 3) == s) {
            float p2 = wp_[(tid >> 7) * PAD + (tid & 127)] * wo_t;
            #pragma unroll
            for (int off = 32; off; off >>= 1) p2 += __shfl_xor(p2, off, 64);
            if ((tid & 63) == 0) red[tid >> 6] = p2;
            __syncthreads();
            if (tid == 0)
                out[(size_t)b * Tc + t] = red[0] + red[1] + red[2] + red[3] +
                                          red[4] + red[5] + red[6] + red[7];
        }

        nz = nz_n; i0 = i0n; i1 = i1n; i2 = i2n;
    }
}

// ---------------------------------------------------------------------------
// Fallback (round-1 kernel) if d_ws is too small — safety net.
// ---------------------------------------------------------------------------
__launch_bounds__(512)
__global__ void rnn_scan_fb(const float* __restrict__ input, const float* __restrict__ noise,
                            const float* __restrict__ w_i, const float* __restrict__ s_i,
                            const float* __restrict__ WT, const float* __restrict__ w_o,
                            const float* __restrict__ s_o, const float* __restrict__ h0,
                            float* __restrict__ out) {
    __shared__ float r_lds[Hc];
    __shared__ float pl[4][Hc];
    __shared__ float wi_lds[Ic][Hc];
    __shared__ float red[8];

    const int tid = threadIdx.x;
    const int b   = blockIdx.x;
    const int g   = tid >> 7;
    const int j   = tid & 127;

    for (int i = 0; i < Ic; ++i) wi_lds[i][tid] = w_i[i * Hc + tid] * s_i[i];

    float h = h0[tid];
    float r_cur = tanhf(h);
    const float wo_h = w_o[tid] * s_o[0] * (1.0f / Hc);
    const float* noise_b = noise + (size_t)b * Tc * Hc;
    const float* inp_b   = input + (size_t)b * Tc * Ic;
    float nz = noise_b[tid];
    float i0 = inp_b[0], i1 = inp_b[1], i2 = inp_b[2];
    const float* Wg = WT + (g * 128) * Hc + 4 * j;
    const float* rg = r_lds + g * 128;
    __syncthreads();

    for (int t = 0; t < Tc; ++t) {
        const int tn = (t + 1 < Tc) ? t + 1 : t;
        const float nz_n = noise_b[(size_t)tn * Hc + tid];
        const float i0n = inp_b[tn * Ic + 0];
        const float i1n = inp_b[tn * Ic + 1];
        const float i2n = inp_b[tn * Ic + 2];

        r_lds[tid] = r_cur;
        __syncthreads();
        float a0 = 0.f, a1 = 0.f, a2 = 0.f, a3 = 0.f;
        #pragma unroll 4
        for (int kk = 0; kk < 128; kk += 4) {
            const float4 rv = *(const float4*)(rg + kk);
            const float4 w0 = *(const float4*)(Wg + (kk + 0) * Hc);
            const float4 w1 = *(const float4*)(Wg + (kk + 1) * Hc);
            const float4 w2 = *(const float4*)(Wg + (kk + 2) * Hc);
            const float4 w3 = *(const float4*)(Wg + (kk + 3) * Hc);
            a0 = fmaf(rv.x, w0.x, a0); a0 = fmaf(rv.y, w1.x, a0);
            a0 = fmaf(rv.z, w2.x, a0); a0 = fmaf(rv.w, w3.x, a0);
            a1 = fmaf(rv.x, w0.y, a1); a1 = fmaf(rv.y, w1.y, a1);
            a1 = fmaf(rv.z, w2.y, a1); a1 = fmaf(rv.w, w3.y, a1);
            a2 = fmaf(rv.x, w0.z, a2); a2 = fmaf(rv.y, w1.z, a2);
            a2 = fmaf(rv.z, w2.z, a2); a2 = fmaf(rv.w, w3.z, a2);
            a3 = fmaf(rv.x, w0.w, a3); a3 = fmaf(rv.y, w1.w, a3);
            a3 = fmaf(rv.z, w2.w, a3); a3 = fmaf(rv.w, w3.w, a3);
        }
        *(float4*)&pl[g][4 * j] = make_float4(a0, a1, a2, a3);
        __syncthreads();

        const float y  = pl[0][tid] + pl[1][tid] + pl[2][tid] + pl[3][tid];
        const float di = i0 * wi_lds[0][tid] + i1 * wi_lds[1][tid] + i2 * wi_lds[2][tid];
        h = h + (NS * nz + AL * di) + AL * (y - h);
        r_cur = tanhf(h);

        float p = r_cur * wo_h;
        #pragma unroll
        for (int off = 32; off; off >>= 1) p += __shfl_xor(p, off, 64);
        if ((tid & 63) == 0) red[tid >> 6] = p;
        __syncthreads();
        if (tid == 0)
            out[(size_t)b * Tc + t] = red[0] + red[1] + red[2] + red[3] +
                                      red[4] + red[5] + red[6] + red[7];
        nz = nz_n; i0 = i0n; i1 = i1n; i2 = i2n;
    }
}

extern "C" void kernel_launch(void* const* d_in, const int* in_sizes, int n_in,
                              void* d_out, int out_size, void* d_ws, size_t ws_size,
                              hipStream_t stream) {
    (void)n_in; (void)out_size;
    const float* input     = (const float*)d_in[0];
    const float* noise     = (const float*)d_in[1];
    const float* w_i       = (const float*)d_in[2];
    const float* s_i       = (const float*)d_in[3];
    const float* m_rec     = (const float*)d_in[4];
    const float* n_rec     = (const float*)d_in[5];
    const float* rec_noise = (const float*)d_in[6];
    const float* w_o       = (const float*)d_in[7];
    const float* s_o       = (const float*)d_in[8];
    const float* h0        = (const float*)d_in[9];
    float* out = (float*)d_out;

    const int R = in_sizes[4] / Hc;

    float* WT = (float*)d_ws;
    const size_t wt_bytes = (size_t)Hc * Hc * sizeof(float);
    const size_t rb_bytes = (size_t)Bc * 2 * Hc * sizeof(unsigned long long);

    prep_wt<<<(Hc * Hc + 255) / 256, 256, 0, stream>>>(m_rec, n_rec, rec_noise, WT, R);

    if (ws_size >= wt_bytes + rb_bytes) {
        unsigned long long* rbuf = (unsigned long long*)((char*)d_ws + wt_bytes);
        hipMemsetAsync(rbuf, 0, rb_bytes, stream);  // reset tags every call (replay-safe)
        rnn4r<<<NSL * Bc, 512, 0, stream>>>(input, noise, w_i, s_i, WT, w_o, s_o, h0,
                                            out, rbuf);
    } else {
        rnn_scan_fb<<<Bc, 512, 0, stream>>>(input, noise, w_i, s_i, WT, w_o, s_o, h0, out);
    }
}